// Round 5
// baseline (418.330 us; speedup 1.0000x reference)
//
#include <hip/hip_runtime.h>
#include <math.h>

// Problem constants (fixed by setup_inputs)
#define M_SEG 128
#define S_SEG 512
#define HD 512
#define NHEAD 8
#define DHEAD 64
#define NROWS (M_SEG * S_SEG)   // 65536
#define QKVLD 1536              // fused qkv row stride
#define GAMMA_F 0.96875f
#define SCALE_F 0.125f          // d^-0.5

typedef unsigned short u16;
typedef float f32x4 __attribute__((ext_vector_type(4)));
typedef __bf16 bf16x8 __attribute__((ext_vector_type(8)));
typedef unsigned short ushort8 __attribute__((ext_vector_type(8)));
typedef unsigned short ushort4v __attribute__((ext_vector_type(4)));

__device__ __forceinline__ u16 f2bf(float f) {
    union { float f; unsigned u; } x; x.f = f;
    unsigned r = x.u + 0x7FFFu + ((x.u >> 16) & 1u);   // RNE
    return (u16)(r >> 16);
}
__device__ __forceinline__ float bf2f(u16 v) {
    union { unsigned u; float f; } x; x.u = ((unsigned)v) << 16;
    return x.f;
}

// async global->LDS, 16B per lane; LDS dest = wave-uniform base + lane*16
__device__ __forceinline__ void gload16(const u16* g, u16* l) {
    __builtin_amdgcn_global_load_lds(
        (const __attribute__((address_space(1))) void*)g,
        (__attribute__((address_space(3))) void*)l, 16, 0, 0);
}

// ---------------------------------------------------------------------------
// fp32 -> bf16, 8 elems/thread
// ---------------------------------------------------------------------------
__global__ __launch_bounds__(256) void convert_bf16(const float* __restrict__ in,
                                                    u16* __restrict__ outp, int n8)
{
    int idx = blockIdx.x * 256 + threadIdx.x;
    if (idx >= n8) return;
    const float4 a = *reinterpret_cast<const float4*>(&in[(size_t)idx * 8]);
    const float4 b = *reinterpret_cast<const float4*>(&in[(size_t)idx * 8 + 4]);
    ushort8 o;
    o[0] = f2bf(a.x); o[1] = f2bf(a.y); o[2] = f2bf(a.z); o[3] = f2bf(a.w);
    o[4] = f2bf(b.x); o[5] = f2bf(b.y); o[6] = f2bf(b.z); o[7] = f2bf(b.w);
    *reinterpret_cast<ushort8*>(&outp[(size_t)idx * 8]) = o;
}

// 4 weights in one launch (blockIdx.y selects), each 512x512
__global__ __launch_bounds__(256) void convert_weights(const float* __restrict__ w0,
                                                       const float* __restrict__ w1,
                                                       const float* __restrict__ w2,
                                                       const float* __restrict__ w3,
                                                       u16* __restrict__ outp)
{
    const int which = blockIdx.y;
    const float* src = which == 0 ? w0 : which == 1 ? w1 : which == 2 ? w2 : w3;
    u16* dst = outp + (size_t)which * 262144;
    int idx = blockIdx.x * 256 + threadIdx.x;        // 32768 per weight
    const float4 a = *reinterpret_cast<const float4*>(&src[(size_t)idx * 8]);
    const float4 b = *reinterpret_cast<const float4*>(&src[(size_t)idx * 8 + 4]);
    ushort8 o;
    o[0] = f2bf(a.x); o[1] = f2bf(a.y); o[2] = f2bf(a.z); o[3] = f2bf(a.w);
    o[4] = f2bf(b.x); o[5] = f2bf(b.y); o[6] = f2bf(b.z); o[7] = f2bf(b.w);
    *reinterpret_cast<ushort8*>(&dst[(size_t)idx * 8]) = o;
}

// ---------------------------------------------------------------------------
// Phase-split 256x256 bf16 MFMA GEMM (NT), K=512, BK=32, 16 K-tiles.
// 3-buffer LDS ring (96 KiB), ONE barrier + ONE counted vmcnt(4) per K-tile.
// Per K-tile, two phases:
//   alpha: vmcnt(4); barrier; sched_barrier; issue A-stage(kt+2);
//          ds_read af[0..3]+bf[0..3]; setprio(1); 16 MFMA; setprio(0)
//   beta:  issue B-stage(kt+2); ds_read af[4..7]; setprio(1); 16 MFMA; setprio(0)
// Ring safety: barrier at kt separates kt-1's reads of buf (kt-1)%3 from
// kt's stage-issue into buf (kt+2)%3 (same buffer).
// vmcnt ledger: 4 loads/thread/K-tile, 2 tiles prefetch -> outstanding 4.
// Swizzle both-sides: gload dest linear, source col = kc^((row>>1)&3),
// frag read applies same XOR -> conflict-free within 16-lane groups.
// 8 waves (2M x 4N), per-wave 128x64 output.
// EPI==0: C bf16 (ldc), coalesced via LDS half-passes.
// EPI==1: res = acc + X(bf16) + bias -> bf16 at Cv (ldc), LDS quarter-passes.
// ---------------------------------------------------------------------------
template<int EPI>
__global__ __launch_bounds__(512, 1) void gemm8p(const u16* __restrict__ A, int lda,
                                                 const u16* __restrict__ B,
                                                 u16* __restrict__ Cv, int ldc, int ntile,
                                                 const u16* __restrict__ Xb,
                                                 const float* __restrict__ bias)
{
    // 3 bufs x (A 256x32 + B 256x32) u16 = 3 x 16384 u16 = 96 KiB
    __shared__ __align__(16) u16 sm[49152];
    const int t    = threadIdx.x;
    const int lane = t & 63;
    const int w    = t >> 6;
    const int wrow = w >> 2;          // 0..1
    const int wcol = w & 3;           // 0..3

    // XCD-bijective blockIdx swizzle (nwg % 8 == 0 in all uses here)
    const int nwg  = gridDim.x;
    const int cpx  = nwg >> 3;
    const int bid  = blockIdx.x;
    const int sbid = (bid & 7) * cpx + (bid >> 3);
    const int mt = sbid / ntile, nt = sbid % ntile;
    const int rowBase = mt * 256, colBase = nt * 256;

    // staging: tile = 1024 chunks of 16B; thread t owns chunks t and t+512
    const int srow = t >> 2;                             // 0..127
    const int sks  = (t & 3) ^ ((srow >> 1) & 3);        // swizzled source k-slot
    const size_t gA0 = (size_t)(rowBase +       srow) * lda + sks * 8;
    const size_t gA1 = (size_t)(rowBase + 128 + srow) * lda + sks * 8;
    const size_t gB0 = (size_t)(colBase +       srow) * HD  + sks * 8;
    const size_t gB1 = (size_t)(colBase + 128 + srow) * HD  + sks * 8;

    f32x4 acc[8][4];
#pragma unroll
    for (int i = 0; i < 8; ++i)
#pragma unroll
        for (int j = 0; j < 4; ++j)
            acc[i][j] = (f32x4){0.f, 0.f, 0.f, 0.f};

#define STAGE_A(kt, buf)                                                     \
    do {                                                                     \
        gload16(&A[gA0 + (kt) * 32], &sm[(buf) * 16384 + t * 8]);            \
        gload16(&A[gA1 + (kt) * 32], &sm[(buf) * 16384 + 4096 + t * 8]);     \
    } while (0)
#define STAGE_B(kt, buf)                                                     \
    do {                                                                     \
        gload16(&B[gB0 + (kt) * 32], &sm[(buf) * 16384 + 8192 + t * 8]);     \
        gload16(&B[gB1 + (kt) * 32], &sm[(buf) * 16384 + 12288 + t * 8]);    \
    } while (0)

    // prologue: tiles 0 and 1 (order matters for the vmcnt ledger)
    STAGE_A(0, 0); STAGE_B(0, 0);
    STAGE_A(1, 1); STAGE_B(1, 1);

    const int frow = lane & 15;
    const int fkc  = lane >> 4;       // 0..3

    // frag LDS u16-offsets (row-dependent XOR applied per read)
#pragma unroll 1
    for (int kt = 0; kt < 16; ++kt) {
        const int buf = kt % 3;
        const int nbuf = (kt + 2) % 3;

        // --- tile boundary: counted wait + single barrier ---
        if (kt < 15) asm volatile("s_waitcnt vmcnt(4)" ::: "memory");
        else         asm volatile("s_waitcnt vmcnt(0)" ::: "memory");
        __builtin_amdgcn_s_barrier();
        __builtin_amdgcn_sched_barrier(0);

        // --- phase alpha ---
        if (kt < 14) STAGE_A(kt + 2, nbuf);
        const u16* Ab = &sm[buf * 16384];
        const u16* Bb = &sm[buf * 16384 + 8192];
        bf16x8 af[4], bfv[4];
#pragma unroll
        for (int mf = 0; mf < 4; ++mf) {
            const int r = wrow * 128 + mf * 16 + frow;
            af[mf] = *reinterpret_cast<const bf16x8*>(&Ab[r * 32 + ((fkc ^ ((r >> 1) & 3)) << 3)]);
        }
#pragma unroll
        for (int nn = 0; nn < 4; ++nn) {
            const int r = wcol * 64 + nn * 16 + frow;
            bfv[nn] = *reinterpret_cast<const bf16x8*>(&Bb[r * 32 + ((fkc ^ ((r >> 1) & 3)) << 3)]);
        }
        __builtin_amdgcn_s_setprio(1);
#pragma unroll
        for (int mf = 0; mf < 4; ++mf)
#pragma unroll
            for (int nn = 0; nn < 4; ++nn)
                acc[mf][nn] = __builtin_amdgcn_mfma_f32_16x16x32_bf16(af[mf], bfv[nn], acc[mf][nn], 0, 0, 0);
        __builtin_amdgcn_s_setprio(0);

        // --- phase beta ---
        if (kt < 14) STAGE_B(kt + 2, nbuf);
#pragma unroll
        for (int mf = 0; mf < 4; ++mf) {
            const int r = wrow * 128 + 64 + mf * 16 + frow;
            af[mf] = *reinterpret_cast<const bf16x8*>(&Ab[r * 32 + ((fkc ^ ((r >> 1) & 3)) << 3)]);
        }
        __builtin_amdgcn_s_setprio(1);
#pragma unroll
        for (int mf = 0; mf < 4; ++mf)
#pragma unroll
            for (int nn = 0; nn < 4; ++nn)
                acc[4 + mf][nn] = __builtin_amdgcn_mfma_f32_16x16x32_bf16(af[mf], bfv[nn], acc[4 + mf][nn], 0, 0, 0);
        __builtin_amdgcn_s_setprio(0);
    }
#undef STAGE_A
#undef STAGE_B

    const int orow = (lane >> 4) * 4;   // C/D: row=(lane>>4)*4+r, col=lane&15
    if (EPI == 0) {
        // two half-passes: 128x256 u16 = 64 KiB in LDS, coalesced ushort8 out
        u16* ldsC = sm;
#pragma unroll
        for (int hp = 0; hp < 2; ++hp) {
            __syncthreads();
            if (wrow == hp) {
#pragma unroll
                for (int mm = 0; mm < 8; ++mm)
#pragma unroll
                    for (int nn = 0; nn < 4; ++nn) {
                        const int row0 = mm * 16 + orow;
                        const int col  = wcol * 64 + nn * 16 + frow;
#pragma unroll
                        for (int r = 0; r < 4; ++r)
                            ldsC[(row0 + r) * 256 + col] = f2bf(acc[mm][nn][r]);
                    }
            }
            __syncthreads();
#pragma unroll
            for (int p = 0; p < 8; ++p) {
                const int lin = p * 512 + t;          // 4096 x 16B chunks
                const int row = lin >> 5, c8 = lin & 31;
                *reinterpret_cast<ushort8*>(
                    &Cv[(size_t)(rowBase + hp * 128 + row) * ldc + colBase + c8 * 8]) =
                    *reinterpret_cast<const ushort8*>(&ldsC[row * 256 + c8 * 8]);
            }
        }
    } else {
        // four quarter-passes: 64x256 f32 = 64 KiB; res = acc + X + bias -> bf16
        float* ldsF = (float*)sm;
#pragma unroll
        for (int q = 0; q < 4; ++q) {
            __syncthreads();
            if (wrow == (q >> 1)) {
#pragma unroll
                for (int mm = 0; mm < 4; ++mm) {
                    const int macc = (q & 1) * 4 + mm;
#pragma unroll
                    for (int nn = 0; nn < 4; ++nn) {
                        const int row0 = mm * 16 + orow;
                        const int col  = wcol * 64 + nn * 16 + frow;
#pragma unroll
                        for (int r = 0; r < 4; ++r)
                            ldsF[(row0 + r) * 256 + col] = acc[macc][nn][r];
                    }
                }
            }
            __syncthreads();
#pragma unroll
            for (int p = 0; p < 8; ++p) {
                const int lin = p * 512 + t;          // 4096 float4 chunks
                const int row = lin >> 6, c4 = lin & 63;
                const int grow = rowBase + q * 64 + row;
                float4 a = *reinterpret_cast<const float4*>(&ldsF[row * 256 + c4 * 4]);
                ushort4v x4 = *reinterpret_cast<const ushort4v*>(
                    &Xb[(size_t)grow * HD + colBase + c4 * 4]);
                float4 b = *reinterpret_cast<const float4*>(&bias[colBase + c4 * 4]);
                ushort4v o;
                o[0] = f2bf(a.x + bf2f(x4[0]) + b.x);
                o[1] = f2bf(a.y + bf2f(x4[1]) + b.y);
                o[2] = f2bf(a.z + bf2f(x4[2]) + b.z);
                o[3] = f2bf(a.w + bf2f(x4[3]) + b.w);
                *reinterpret_cast<ushort4v*>(
                    &Cv[(size_t)grow * ldc + colBase + c4 * 4]) = o;
            }
        }
    }
}

// ---------------------------------------------------------------------------
// A[m,h,d,e] = sum_s k[m,s,d] * v[m,s,e] from fused qkv (stride 1536).
// 64 threads (1 wave) per (h,m); 8x8 microtile per thread (halves LDS
// traffic per FLOP vs 4x4); grid 1024 = exactly 1 wave/SIMD device-wide.
// ---------------------------------------------------------------------------
__global__ __launch_bounds__(64) void kv_outer(const u16* __restrict__ qkv,
                                               float* __restrict__ Abuf)
{
    __shared__ __align__(16) float Ks[32][64];
    __shared__ __align__(16) float Vs[32][64];
    const int t  = threadIdx.x;
    const int hh = blockIdx.x;
    const int m  = blockIdx.y;
    const int d0 = (t >> 3) * 8;
    const int e0 = (t & 7) * 8;
    float acc[8][8] = {};

    for (int s0 = 0; s0 < S_SEG; s0 += 32) {
#pragma unroll
        for (int i = 0; i < 4; ++i) {
            const int slot = i * 64 + t;           // 256 slots: s=slot>>3, c8=slot&7
            const int s  = slot >> 3;
            const int c8 = slot & 7;
            size_t g = (size_t)(m * S_SEG + s0 + s) * QKVLD + hh * DHEAD + c8 * 8;
            bf16x8 k8 = *reinterpret_cast<const bf16x8*>(&qkv[g + 512]);    // k
            bf16x8 v8 = *reinterpret_cast<const bf16x8*>(&qkv[g + 1024]);   // v
            float kf[8], vf[8];
#pragma unroll
            for (int j = 0; j < 8; ++j) { kf[j] = (float)k8[j]; vf[j] = (float)v8[j]; }
            *reinterpret_cast<float4*>(&Ks[s][c8 * 8])     = make_float4(kf[0], kf[1], kf[2], kf[3]);
            *reinterpret_cast<float4*>(&Ks[s][c8 * 8 + 4]) = make_float4(kf[4], kf[5], kf[6], kf[7]);
            *reinterpret_cast<float4*>(&Vs[s][c8 * 8])     = make_float4(vf[0], vf[1], vf[2], vf[3]);
            *reinterpret_cast<float4*>(&Vs[s][c8 * 8 + 4]) = make_float4(vf[4], vf[5], vf[6], vf[7]);
        }
        __syncthreads();
#pragma unroll
        for (int s = 0; s < 32; ++s) {
            float4 ka = *reinterpret_cast<const float4*>(&Ks[s][d0]);
            float4 kb = *reinterpret_cast<const float4*>(&Ks[s][d0 + 4]);
            float4 va = *reinterpret_cast<const float4*>(&Vs[s][e0]);
            float4 vb = *reinterpret_cast<const float4*>(&Vs[s][e0 + 4]);
            float kv[8] = {ka.x, ka.y, ka.z, ka.w, kb.x, kb.y, kb.z, kb.w};
            float vv[8] = {va.x, va.y, va.z, va.w, vb.x, vb.y, vb.z, vb.w};
#pragma unroll
            for (int i = 0; i < 8; ++i)
#pragma unroll
                for (int j = 0; j < 8; ++j)
                    acc[i][j] = fmaf(kv[i], vv[j], acc[i][j]);
        }
        __syncthreads();
    }

#pragma unroll
    for (int i = 0; i < 8; ++i) {
        size_t base = ((size_t)(m * NHEAD + hh) * DHEAD + d0 + i) * DHEAD + e0;
        *reinterpret_cast<float4*>(&Abuf[base])     = make_float4(acc[i][0], acc[i][1], acc[i][2], acc[i][3]);
        *reinterpret_cast<float4*>(&Abuf[base + 4]) = make_float4(acc[i][4], acc[i][5], acc[i][6], acc[i][7]);
    }
}

// ---------------------------------------------------------------------------
// r_m = A_m + decay*r_{m-1} ;  Bc_m = scale*A_m + gamma^{m+1} * r_m  (fp32)
// ---------------------------------------------------------------------------
__global__ __launch_bounds__(256) void scan_kernel(const float* __restrict__ Abuf,
                                                   float* __restrict__ Bc)
{
    const int tid = blockIdx.x * 256 + threadIdx.x;   // 0..32767
    const float decay = powf(GAMMA_F, (float)S_SEG);
    float r = 0.0f;
    float g = 1.0f;
    for (int m = 0; m < M_SEG; ++m) {
        float a = Abuf[(size_t)m * 32768 + tid];
        r = fmaf(decay, r, a);
        g *= GAMMA_F;
        Bc[(size_t)m * 32768 + tid] = fmaf(g, r, SCALE_F * a);
    }
}

// ---------------------------------------------------------------------------
// h = relu(q @ Bc) written IN PLACE into qkv's q-slot
// ---------------------------------------------------------------------------
__global__ __launch_bounds__(256) void h_mfma(u16* __restrict__ qkv,
                                              const float* __restrict__ Bc)
{
    __shared__ __align__(16) u16 BT[64 * 72];    // Bc^T [e][d], pad 72
    const int t    = threadIdx.x;
    const int lane = t & 63;
    const int w    = t >> 6;
    const int m    = blockIdx.y;
    const int sBase = blockIdx.x * 256 + w * 64;
    const int frow = lane & 15;
    const int fkc  = lane >> 4;

    for (int hh = 0; hh < NHEAD; ++hh) {
#pragma unroll
        for (int i = 0; i < 4; ++i) {
            int idx = t + i * 256;               // 1024 float4s
            int d = idx >> 4, e4 = idx & 15;
            float4 v = *reinterpret_cast<const float4*>(
                &Bc[((size_t)(m * NHEAD + hh) * DHEAD + d) * DHEAD + e4 * 4]);
            BT[(e4 * 4 + 0) * 72 + d] = f2bf(v.x);
            BT[(e4 * 4 + 1) * 72 + d] = f2bf(v.y);
            BT[(e4 * 4 + 2) * 72 + d] = f2bf(v.z);
            BT[(e4 * 4 + 3) * 72 + d] = f2bf(v.w);
        }
        __syncthreads();

        f32x4 acc[4][4];
#pragma unroll
        for (int i = 0; i < 4; ++i)
#pragma unroll
            for (int j = 0; j < 4; ++j)
                acc[i][j] = (f32x4){0.f, 0.f, 0.f, 0.f};

#pragma unroll
        for (int ks = 0; ks < 2; ++ks) {
            bf16x8 af[4], bfr[4];
#pragma unroll
            for (int mm = 0; mm < 4; ++mm) {
                const int grow = m * S_SEG + sBase + mm * 16 + frow;
                af[mm] = *reinterpret_cast<const bf16x8*>(
                    &qkv[(size_t)grow * QKVLD + hh * DHEAD + ks * 32 + fkc * 8]);
                const int e = mm * 16 + frow;
                bfr[mm] = *reinterpret_cast<const bf16x8*>(&BT[e * 72 + ks * 32 + fkc * 8]);
            }
#pragma unroll
            for (int mm = 0; mm < 4; ++mm)
#pragma unroll
                for (int nn = 0; nn < 4; ++nn)
                    acc[mm][nn] = __builtin_amdgcn_mfma_f32_16x16x32_bf16(af[mm], bfr[nn], acc[mm][nn], 0, 0, 0);
        }

        const int orow = (lane >> 4) * 4;
#pragma unroll
        for (int mm = 0; mm < 4; ++mm)
#pragma unroll
            for (int nn = 0; nn < 4; ++nn) {
                const int col  = hh * DHEAD + nn * 16 + frow;
                const int row0 = m * S_SEG + sBase + mm * 16 + orow;
#pragma unroll
                for (int r = 0; r < 4; ++r)
                    qkv[(size_t)(row0 + r) * QKVLD + col] = f2bf(fmaxf(acc[mm][nn][r], 0.f));
            }
        __syncthreads();
    }
}

// ---------------------------------------------------------------------------
// GroupNorm from bf16 res (qkv k-slot, stride 1536) -> fp32 d_out rows 1..N
// ---------------------------------------------------------------------------
__global__ __launch_bounds__(256) void groupnorm_bf16(const u16* __restrict__ res,
                                                      float* __restrict__ out,
                                                      const float* __restrict__ gn_w,
                                                      const float* __restrict__ gn_b)
{
    const int g = blockIdx.x;
    const int m = blockIdx.y;
    const int t = threadIdx.x;
    const u16* base = res + (size_t)(m * S_SEG) * QKVLD + g * DHEAD;

    float sum = 0.0f, sq = 0.0f;
    for (int idx = t; idx < 4096; idx += 256) {      // 512 rows x 8 ushort8
        int s = idx >> 3, c8 = idx & 7;
        ushort8 v = *reinterpret_cast<const ushort8*>(&base[(size_t)s * QKVLD + c8 * 8]);
#pragma unroll
        for (int j = 0; j < 8; ++j) {
            float f = bf2f(v[j]);
            sum += f; sq += f * f;
        }
    }
    __shared__ float rs[256], rq[256];
    rs[t] = sum; rq[t] = sq;
    __syncthreads();
    for (int off = 128; off > 0; off >>= 1) {
        if (t < off) { rs[t] += rs[t + off]; rq[t] += rq[t + off]; }
        __syncthreads();
    }
    __shared__ float smean, sinv;
    if (t == 0) {
        float mean = rs[0] * (1.0f / 32768.0f);
        float var  = rq[0] * (1.0f / 32768.0f) - mean * mean;
        smean = mean;
        sinv  = rsqrtf(var + 1e-5f);
    }
    __syncthreads();
    const float mean = smean, inv = sinv;

    for (int idx = t; idx < 4096; idx += 256) {
        int s = idx >> 3, c8 = idx & 7;
        ushort8 v = *reinterpret_cast<const ushort8*>(&base[(size_t)s * QKVLD + c8 * 8]);
        float o[8];
#pragma unroll
        for (int j = 0; j < 8; ++j) {
            float wj = gn_w[g * DHEAD + c8 * 8 + j];
            float bj = gn_b[g * DHEAD + c8 * 8 + j];
            o[j] = (bf2f(v[j]) - mean) * inv * wj + bj;
        }
        float* dst = &out[(size_t)(1 + m * S_SEG + s) * HD + g * DHEAD + c8 * 8];
        *reinterpret_cast<float4*>(dst)     = make_float4(o[0], o[1], o[2], o[3]);
        *reinterpret_cast<float4*>(dst + 4) = make_float4(o[4], o[5], o[6], o[7]);
    }
}

__global__ void zero_row(float* __restrict__ out)
{
    int i = blockIdx.x * 256 + threadIdx.x;
    if (i < HD) out[i] = 0.0f;
}

// ---------------------------------------------------------------------------
extern "C" void kernel_launch(void* const* d_in, const int* in_sizes, int n_in,
                              void* d_out, int out_size, void* d_ws, size_t ws_size,
                              hipStream_t stream)
{
    const float* msg = (const float*)d_in[0];
    const float* Wq  = (const float*)d_in[1];
    const float* Wk  = (const float*)d_in[2];
    const float* Wv  = (const float*)d_in[3];
    const float* Wo  = (const float*)d_in[4];
    const float* bo  = (const float*)d_in[5];
    const float* gnw = (const float*)d_in[6];
    const float* gnb = (const float*)d_in[7];
    float* out = (float*)d_out;

    // d_out scratch (consumed before groupnorm rewrites d_out):
    //   msgb bf16 (67.1 MB) | Abuf fp32 (16.8 MB) | Bc fp32 (16.8 MB)
    u16*   msgb = (u16*)out;
    float* Abuf = out + 16777216;
    float* Bc   = out + 16777216 + 4194304;

    // d_ws: Wb 2 MB (Wq|Wk|Wv|Wo bf16) + qkv 201.3 MB (65536 x 1536).
    // h_mfma overwrites qkv's q-slot with h; EPI gemm writes bf16 res into
    // qkv's k-slot (dead after kv_outer).
    u16* Wb  = (u16*)d_ws;
    u16* qkv = Wb + 4 * 262144;
    u16* resB = qkv + 512;    // res bf16, stride 1536

    convert_weights<<<dim3(128, 4), 256, 0, stream>>>(Wq, Wk, Wv, Wo, Wb);
    convert_bf16<<<16384, 256, 0, stream>>>(msg, msgb, 4194304);

    // fused QKV GEMM: A=msgb (65536x512), B=[Wq;Wk;Wv] (1536x512) -> qkv
    gemm8p<0><<<1536, 512, 0, stream>>>(msgb, HD, Wb, qkv, QKVLD, 6, nullptr, nullptr);

    kv_outer<<<dim3(NHEAD, M_SEG), 64, 0, stream>>>(qkv, Abuf);
    scan_kernel<<<128, 256, 0, stream>>>(Abuf, Bc);
    h_mfma<<<dim3(2, M_SEG), 256, 0, stream>>>(qkv, Bc);

    // output GEMM: A=h (qkv q-slot, lda=1536), B=Wo; res=acc+msgb+bias -> bf16
    gemm8p<1><<<512, 512, 0, stream>>>(qkv, QKVLD, Wb + 3 * 262144, resB, QKVLD, 2, msgb, bo);

    zero_row<<<2, 256, 0, stream>>>(out);
    groupnorm_bf16<<<dim3(8, M_SEG), 256, 0, stream>>>(resB, out, gnw, gnb);
}